// Round 1
// baseline (118.065 us; speedup 1.0000x reference)
//
#include <hip/hip_runtime.h>

// ---------------- problem constants (match setup_inputs) ----------------
#define NROWS 8192
#define DDIM  128
#define SPLIT 32                 // j-splits per GEMM pass
#define JCOLS (NROWS / SPLIT)    // 256 columns per block
#define NTILE (JCOLS / 16)       // 16 j-tiles per block
#define LAMDA 0.5f
#define EPSV  1e-5f
#define LN2F  0.69314718055994530942f
// sqrt(log2(e)/T), T = 0.07 -> MFMA output = sim * log2(e) / T (exp2 argument)
#define FSCALE 4.53981643f

typedef short s16x8 __attribute__((ext_vector_type(8)));
typedef float f32x4 __attribute__((ext_vector_type(4)));
typedef unsigned short u16;
typedef unsigned int u32;

__device__ __forceinline__ u16 f2bf(float x) {
  u32 b = __builtin_bit_cast(u32, x);
  u32 r = (b + 0x7FFFu + ((b >> 16) & 1u)) >> 16;   // RNE
  return (u16)r;
}

// ---------------- kernel 1: normalize + scale + bf16 ----------------
__global__ __launch_bounds__(256) void norm_kernel(
    const float* __restrict__ feat, u16* __restrict__ g) {
  int wave = threadIdx.x >> 6;
  int lane = threadIdx.x & 63;
  int row = (blockIdx.x << 2) + wave;
  const float* fr = feat + (size_t)row * DDIM + (lane << 1);
  float2 v = *(const float2*)fr;
  float ss = v.x * v.x + v.y * v.y;
#pragma unroll
  for (int m = 1; m < 64; m <<= 1) ss += __shfl_xor(ss, m);
  float inv = FSCALE / fmaxf(sqrtf(ss), 1e-12f);
  ushort2 o;
  o.x = f2bf(v.x * inv);
  o.y = f2bf(v.y * inv);
  *(ushort2*)(g + (size_t)row * DDIM + (lane << 1)) = o;
}

// ---------------- kernel 2: denominator partials ----------------
// grid (NROWS/128, SPLIT), block 256.  pdenom[split][i] = sum_{j in split, j!=i} w*exp(sim)
__global__ __launch_bounds__(256) void denom_kernel(
    const u16* __restrict__ g, const int* __restrict__ dom,
    float* __restrict__ pdenom) {
  __shared__ u16 Bs[16 * 128];
  const int tid = threadIdx.x;
  const int wave = tid >> 6, lane = tid & 63;
  const int lr = lane & 15, lh = lane >> 4;
  const int i0 = blockIdx.x * 128 + wave * 32;
  const int j0 = blockIdx.y * JCOLS;

  // A fragments: rows i0 + rf*16 + lr, k-chunk kc*32 + lh*8
  s16x8 a[2][4];
#pragma unroll
  for (int rf = 0; rf < 2; ++rf) {
    const u16* gr = g + (size_t)(i0 + rf * 16 + lr) * DDIM + lh * 8;
#pragma unroll
    for (int kc = 0; kc < 4; ++kc) a[rf][kc] = *(const s16x8*)(gr + kc * 32);
  }
  int di[2][4];
#pragma unroll
  for (int rf = 0; rf < 2; ++rf)
#pragma unroll
    for (int r = 0; r < 4; ++r) di[rf][r] = dom[i0 + rf * 16 + lh * 4 + r];

  float dacc[2][4] = {};

  // LDS staging: thread t -> row t>>4, chunk t&15, XOR-swizzled slot
  const int stg_r = tid >> 4, stg_c = tid & 15;
  const int stg_dst = stg_r * 128 + ((stg_c ^ (stg_r & 7)) << 3);
  const u16* stg_src = g + (size_t)(j0 + stg_r) * DDIM + (stg_c << 3);

  for (int jt = 0; jt < NTILE; ++jt) {
    __syncthreads();
    *(uint4*)(&Bs[stg_dst]) = *(const uint4*)(stg_src + (size_t)jt * 16 * DDIM);
    __syncthreads();

    s16x8 b[4];
#pragma unroll
    for (int kc = 0; kc < 4; ++kc) {
      int c = (kc << 2) + lh;
      b[kc] = *(const s16x8*)(&Bs[lr * 128 + ((c ^ (lr & 7)) << 3)]);
    }
    f32x4 acc[2] = {f32x4{0.f, 0.f, 0.f, 0.f}, f32x4{0.f, 0.f, 0.f, 0.f}};
#pragma unroll
    for (int kc = 0; kc < 4; ++kc) {
      acc[0] = __builtin_amdgcn_mfma_f32_16x16x32_bf16(a[0][kc], b[kc], acc[0], 0, 0, 0);
      acc[1] = __builtin_amdgcn_mfma_f32_16x16x32_bf16(a[1][kc], b[kc], acc[1], 0, 0, 0);
    }
    const int gj = j0 + jt * 16 + lr;
    const int dj = dom[gj];
#pragma unroll
    for (int rf = 0; rf < 2; ++rf)
#pragma unroll
      for (int r = 0; r < 4; ++r) {
        int gi = i0 + rf * 16 + lh * 4 + r;
        float w = (di[rf][r] == dj) ? LAMDA : (1.0f - LAMDA);
        float e = w * exp2f(acc[rf][r]);
        dacc[rf][r] += (gi == gj) ? 0.0f : e;
      }
  }
#pragma unroll
  for (int rf = 0; rf < 2; ++rf)
#pragma unroll
    for (int r = 0; r < 4; ++r) {
      float v = dacc[rf][r];
      v += __shfl_xor(v, 1); v += __shfl_xor(v, 2);
      v += __shfl_xor(v, 4); v += __shfl_xor(v, 8);
      if (lr == 0)
        pdenom[(size_t)blockIdx.y * NROWS + i0 + rf * 16 + lh * 4 + r] = v;
    }
}

// ---------------- kernel 3: reduce denom partials -> 1/denom ----------------
__global__ __launch_bounds__(256) void denom_reduce(
    const float* __restrict__ pdenom, float* __restrict__ invd) {
  int i = blockIdx.x * 256 + threadIdx.x;
  float s = 0.f;
#pragma unroll
  for (int k = 0; k < SPLIT; ++k) s += pdenom[(size_t)k * NROWS + i];
  s += EPSV;
  invd[i] = 1.0f / s;
}

// ---------------- kernel 4: loss partials ----------------
__global__ __launch_bounds__(256) void loss_kernel(
    const u16* __restrict__ g, const int* __restrict__ lab,
    const int* __restrict__ dom, const float* __restrict__ invd,
    float* __restrict__ ploss, int* __restrict__ pnp) {
  __shared__ u16 Bs[16 * 128];
  const int tid = threadIdx.x;
  const int wave = tid >> 6, lane = tid & 63;
  const int lr = lane & 15, lh = lane >> 4;
  const int i0 = blockIdx.x * 128 + wave * 32;
  const int j0 = blockIdx.y * JCOLS;

  s16x8 a[2][4];
#pragma unroll
  for (int rf = 0; rf < 2; ++rf) {
    const u16* gr = g + (size_t)(i0 + rf * 16 + lr) * DDIM + lh * 8;
#pragma unroll
    for (int kc = 0; kc < 4; ++kc) a[rf][kc] = *(const s16x8*)(gr + kc * 32);
  }
  int li[2][4], di[2][4];
  float vi[2][4];
#pragma unroll
  for (int rf = 0; rf < 2; ++rf)
#pragma unroll
    for (int r = 0; r < 4; ++r) {
      int gi = i0 + rf * 16 + lh * 4 + r;
      li[rf][r] = lab[gi];
      di[rf][r] = dom[gi];
      vi[rf][r] = invd[gi];
    }

  float lacc[2][4] = {};
  int npacc[2][4] = {};

  const int stg_r = tid >> 4, stg_c = tid & 15;
  const int stg_dst = stg_r * 128 + ((stg_c ^ (stg_r & 7)) << 3);
  const u16* stg_src = g + (size_t)(j0 + stg_r) * DDIM + (stg_c << 3);

  for (int jt = 0; jt < NTILE; ++jt) {
    __syncthreads();
    *(uint4*)(&Bs[stg_dst]) = *(const uint4*)(stg_src + (size_t)jt * 16 * DDIM);
    __syncthreads();

    s16x8 b[4];
#pragma unroll
    for (int kc = 0; kc < 4; ++kc) {
      int c = (kc << 2) + lh;
      b[kc] = *(const s16x8*)(&Bs[lr * 128 + ((c ^ (lr & 7)) << 3)]);
    }
    f32x4 acc[2] = {f32x4{0.f, 0.f, 0.f, 0.f}, f32x4{0.f, 0.f, 0.f, 0.f}};
#pragma unroll
    for (int kc = 0; kc < 4; ++kc) {
      acc[0] = __builtin_amdgcn_mfma_f32_16x16x32_bf16(a[0][kc], b[kc], acc[0], 0, 0, 0);
      acc[1] = __builtin_amdgcn_mfma_f32_16x16x32_bf16(a[1][kc], b[kc], acc[1], 0, 0, 0);
    }
    const int gj = j0 + jt * 16 + lr;
    const int lj = lab[gj];
    const int dj = dom[gj];
#pragma unroll
    for (int rf = 0; rf < 2; ++rf)
#pragma unroll
      for (int r = 0; r < 4; ++r) {
        int gi = i0 + rf * 16 + lh * 4 + r;
        bool pos = (li[rf][r] == lj) && (gi != gj);
        float w = (di[rf][r] == dj) ? LAMDA : (1.0f - LAMDA);
        float x = w * exp2f(acc[rf][r]) * vi[rf][r] + EPSV;
        float lf = log2f(x);
        lacc[rf][r] += pos ? lf : 0.0f;
        npacc[rf][r] += pos ? 1 : 0;
      }
  }
#pragma unroll
  for (int rf = 0; rf < 2; ++rf)
#pragma unroll
    for (int r = 0; r < 4; ++r) {
      float v = lacc[rf][r];
      int n = npacc[rf][r];
      v += __shfl_xor(v, 1); v += __shfl_xor(v, 2);
      v += __shfl_xor(v, 4); v += __shfl_xor(v, 8);
      n += __shfl_xor(n, 1); n += __shfl_xor(n, 2);
      n += __shfl_xor(n, 4); n += __shfl_xor(n, 8);
      if (lr == 0) {
        size_t idx = (size_t)blockIdx.y * NROWS + i0 + rf * 16 + lh * 4 + r;
        ploss[idx] = v;
        pnp[idx] = n;
      }
    }
}

// ---------------- kernel 5: per-row finalize ----------------
__global__ __launch_bounds__(256) void row_finalize(
    const float* __restrict__ ploss, const int* __restrict__ pnp,
    float* __restrict__ rowloss, int* __restrict__ rowvalid) {
  int i = blockIdx.x * 256 + threadIdx.x;
  float l = 0.f;
  int np = 0;
#pragma unroll
  for (int k = 0; k < SPLIT; ++k) {
    l += ploss[(size_t)k * NROWS + i];
    np += pnp[(size_t)k * NROWS + i];
  }
  rowvalid[i] = (np > 0) ? 1 : 0;
  rowloss[i] = (np > 0) ? (l * LN2F / (float)np) : 0.0f;
}

// ---------------- kernel 6: final scalar ----------------
__global__ __launch_bounds__(256) void final_reduce(
    const float* __restrict__ rowloss, const int* __restrict__ rowvalid,
    float* __restrict__ out) {
  __shared__ float sL[256];
  __shared__ int sV[256];
  int tid = threadIdx.x;
  float a = 0.f;
  int v = 0;
  for (int i = tid; i < NROWS; i += 256) {
    a += rowloss[i];
    v += rowvalid[i];
  }
  sL[tid] = a; sV[tid] = v;
  __syncthreads();
  for (int s = 128; s > 0; s >>= 1) {
    if (tid < s) { sL[tid] += sL[tid + s]; sV[tid] += sV[tid + s]; }
    __syncthreads();
  }
  if (tid == 0) {
    // N - nans + 1 == valid_count + 1
    out[0] = -sL[0] / (float)(sV[0] + 1);
  }
}

// ---------------- launch ----------------
extern "C" void kernel_launch(void* const* d_in, const int* in_sizes, int n_in,
                              void* d_out, int out_size, void* d_ws, size_t ws_size,
                              hipStream_t stream) {
  const float* feat = (const float*)d_in[0];
  const int* labels = (const int*)d_in[1];
  const int* doms = (const int*)d_in[2];
  float* out = (float*)d_out;

  char* ws = (char*)d_ws;
  u16* g        = (u16*)(ws);                         // 2 MB
  float* pdenom = (float*)(ws + (2u << 20));          // 1 MB
  float* ploss  = (float*)(ws + (3u << 20));          // 1 MB
  int* pnp      = (int*)(ws + (4u << 20));            // 1 MB
  float* invd   = (float*)(ws + (5u << 20));          // 32 KB
  float* rowloss= (float*)(ws + (5u << 20) + 32768);  // 32 KB
  int* rowvalid = (int*)(ws + (5u << 20) + 65536);    // 32 KB

  norm_kernel<<<NROWS / 4, 256, 0, stream>>>(feat, g);
  denom_kernel<<<dim3(NROWS / 128, SPLIT), 256, 0, stream>>>(g, doms, pdenom);
  denom_reduce<<<NROWS / 256, 256, 0, stream>>>(pdenom, invd);
  loss_kernel<<<dim3(NROWS / 128, SPLIT), 256, 0, stream>>>(g, labels, doms, invd, ploss, pnp);
  row_finalize<<<NROWS / 256, 256, 0, stream>>>(ploss, pnp, rowloss, rowvalid);
  final_reduce<<<1, 256, 0, stream>>>(rowloss, rowvalid, out);
}

// Round 2
// 94.233 us; speedup vs baseline: 1.2529x; 1.2529x over previous
//
#include <hip/hip_runtime.h>

// ---------------- problem constants (match setup_inputs) ----------------
#define NROWS 8192
#define DDIM  128
#define SPLIT 32                 // j-splits per GEMM pass
#define JCOLS (NROWS / SPLIT)    // 256 columns per block
#define NTILE (JCOLS / 16)       // 16 j-tiles per block
#define EPSV  1e-5f
#define LN2F  0.69314718055994530942f
// sqrt(log2(e)/T), T = 0.07 -> MFMA output = sim * log2(e) / T (exp2 argument)
#define FSCALE 4.53981643f

typedef short s16x8 __attribute__((ext_vector_type(8)));
typedef float f32x4 __attribute__((ext_vector_type(4)));
typedef unsigned short u16;
typedef unsigned int u32;

__device__ __forceinline__ u16 f2bf(float x) {
  u32 b = __builtin_bit_cast(u32, x);
  u32 r = (b + 0x7FFFu + ((b >> 16) & 1u)) >> 16;   // RNE
  return (u16)r;
}

// ---------------- kernel 1: normalize + scale + bf16 ----------------
__global__ __launch_bounds__(256) void norm_kernel(
    const float* __restrict__ feat, u16* __restrict__ g) {
  int wave = threadIdx.x >> 6;
  int lane = threadIdx.x & 63;
  int row = (blockIdx.x << 2) + wave;
  const float* fr = feat + (size_t)row * DDIM + (lane << 1);
  float2 v = *(const float2*)fr;
  float ss = v.x * v.x + v.y * v.y;
#pragma unroll
  for (int m = 1; m < 64; m <<= 1) ss += __shfl_xor(ss, m);
  float inv = FSCALE / fmaxf(sqrtf(ss), 1e-12f);
  ushort2 o;
  o.x = f2bf(v.x * inv);
  o.y = f2bf(v.y * inv);
  *(ushort2*)(g + (size_t)row * DDIM + (lane << 1)) = o;
}

// ---------------- kernel 1b: label histogram (num_pos for free) -------------
__global__ __launch_bounds__(256) void hist_kernel(
    const int* __restrict__ lab, int* __restrict__ cnt) {
  __shared__ int h[128];
  int tid = threadIdx.x;
  if (tid < 128) h[tid] = 0;
  __syncthreads();
  for (int i = tid; i < NROWS; i += 256) atomicAdd(&h[lab[i]], 1);
  __syncthreads();
  if (tid < 128) cnt[tid] = h[tid];
}

// ---------------- kernel 2: denominator partials ----------------
// grid (NROWS/128, SPLIT), block 256.
// pdenom[split][i] = sum_{j in split, j!=i} 0.5*exp(sim_ij)
// Trick: acc initialized to -1 -> exp2(acc) = 0.5*exp(sim).
__global__ __launch_bounds__(256) void denom_kernel(
    const u16* __restrict__ g, float* __restrict__ pdenom) {
  __shared__ u16 Bs[16 * 128];
  const int tid = threadIdx.x;
  const int wave = tid >> 6, lane = tid & 63;
  const int lr = lane & 15, lh = lane >> 4;
  const int i0 = blockIdx.x * 128 + wave * 32;
  const int j0 = blockIdx.y * JCOLS;

  // A fragments: rows i0 + rf*16 + lr, k-chunk kc*32 + lh*8
  s16x8 a[2][4];
#pragma unroll
  for (int rf = 0; rf < 2; ++rf) {
    const u16* gr = g + (size_t)(i0 + rf * 16 + lr) * DDIM + lh * 8;
#pragma unroll
    for (int kc = 0; kc < 4; ++kc) a[rf][kc] = *(const s16x8*)(gr + kc * 32);
  }
  int gibase[2];
  gibase[0] = i0 + lh * 4;
  gibase[1] = i0 + 16 + lh * 4;

  float dacc[2][4] = {};

  const int stg_r = tid >> 4, stg_c = tid & 15;
  const int stg_dst = stg_r * 128 + ((stg_c ^ (stg_r & 7)) << 3);
  const u16* stg_src = g + (size_t)(j0 + stg_r) * DDIM + (stg_c << 3);

  for (int jt = 0; jt < NTILE; ++jt) {
    __syncthreads();
    *(uint4*)(&Bs[stg_dst]) = *(const uint4*)(stg_src + (size_t)jt * 16 * DDIM);
    __syncthreads();

    s16x8 b[4];
#pragma unroll
    for (int kc = 0; kc < 4; ++kc) {
      int c = (kc << 2) + lh;
      b[kc] = *(const s16x8*)(&Bs[lr * 128 + ((c ^ (lr & 7)) << 3)]);
    }
    f32x4 acc[2] = {f32x4{-1.f, -1.f, -1.f, -1.f}, f32x4{-1.f, -1.f, -1.f, -1.f}};
#pragma unroll
    for (int kc = 0; kc < 4; ++kc) {
      acc[0] = __builtin_amdgcn_mfma_f32_16x16x32_bf16(a[0][kc], b[kc], acc[0], 0, 0, 0);
      acc[1] = __builtin_amdgcn_mfma_f32_16x16x32_bf16(a[1][kc], b[kc], acc[1], 0, 0, 0);
    }
    const int tj0 = j0 + jt * 16;
    if (tj0 == i0 || tj0 == i0 + 16) {
      const int gj = tj0 + lr;
#pragma unroll
      for (int rf = 0; rf < 2; ++rf)
#pragma unroll
        for (int r = 0; r < 4; ++r) {
          float e = __builtin_amdgcn_exp2f(acc[rf][r]);
          dacc[rf][r] += (gibase[rf] + r == gj) ? 0.0f : e;
        }
    } else {
#pragma unroll
      for (int rf = 0; rf < 2; ++rf)
#pragma unroll
        for (int r = 0; r < 4; ++r)
          dacc[rf][r] += __builtin_amdgcn_exp2f(acc[rf][r]);
    }
  }
#pragma unroll
  for (int rf = 0; rf < 2; ++rf)
#pragma unroll
    for (int r = 0; r < 4; ++r) {
      float v = dacc[rf][r];
      v += __shfl_xor(v, 1); v += __shfl_xor(v, 2);
      v += __shfl_xor(v, 4); v += __shfl_xor(v, 8);
      if (lr == 0)
        pdenom[(size_t)blockIdx.y * NROWS + gibase[rf] + r] = v;
    }
}

// ---------------- kernel 3: reduce denom partials -> log2(1/denom) ---------
__global__ __launch_bounds__(256) void denom_reduce(
    const float* __restrict__ pdenom, float* __restrict__ li2) {
  int i = blockIdx.x * 256 + threadIdx.x;
  float s = 0.f;
#pragma unroll
  for (int k = 0; k < SPLIT; ++k) s += pdenom[(size_t)k * NROWS + i];
  s += EPSV;
  li2[i] = -__builtin_amdgcn_logf(s);   // v_log_f32 = log2
}

// ---------------- kernel 4: loss partials ----------------
// ploss[split][i] = sum_{pos j in split} log2(0.5*exp(sim)/denom + EPS)
__global__ __launch_bounds__(256) void loss_kernel(
    const u16* __restrict__ g, const int* __restrict__ lab,
    const float* __restrict__ li2, float* __restrict__ ploss) {
  __shared__ u16 Bs[16 * 128];
  const int tid = threadIdx.x;
  const int wave = tid >> 6, lane = tid & 63;
  const int lr = lane & 15, lh = lane >> 4;
  const int i0 = blockIdx.x * 128 + wave * 32;
  const int j0 = blockIdx.y * JCOLS;

  s16x8 a[2][4];
#pragma unroll
  for (int rf = 0; rf < 2; ++rf) {
    const u16* gr = g + (size_t)(i0 + rf * 16 + lr) * DDIM + lh * 8;
#pragma unroll
    for (int kc = 0; kc < 4; ++kc) a[rf][kc] = *(const s16x8*)(gr + kc * 32);
  }
  int li[2][4];
  float l2i[2][4];
  int gibase[2];
  gibase[0] = i0 + lh * 4;
  gibase[1] = i0 + 16 + lh * 4;
#pragma unroll
  for (int rf = 0; rf < 2; ++rf)
#pragma unroll
    for (int r = 0; r < 4; ++r) {
      int gi = gibase[rf] + r;
      li[rf][r] = lab[gi];
      l2i[rf][r] = li2[gi];
    }

  float lacc[2][4] = {};

  const int stg_r = tid >> 4, stg_c = tid & 15;
  const int stg_dst = stg_r * 128 + ((stg_c ^ (stg_r & 7)) << 3);
  const u16* stg_src = g + (size_t)(j0 + stg_r) * DDIM + (stg_c << 3);

  for (int jt = 0; jt < NTILE; ++jt) {
    __syncthreads();
    *(uint4*)(&Bs[stg_dst]) = *(const uint4*)(stg_src + (size_t)jt * 16 * DDIM);
    __syncthreads();

    s16x8 b[4];
#pragma unroll
    for (int kc = 0; kc < 4; ++kc) {
      int c = (kc << 2) + lh;
      b[kc] = *(const s16x8*)(&Bs[lr * 128 + ((c ^ (lr & 7)) << 3)]);
    }
    f32x4 acc[2] = {f32x4{-1.f, -1.f, -1.f, -1.f}, f32x4{-1.f, -1.f, -1.f, -1.f}};
#pragma unroll
    for (int kc = 0; kc < 4; ++kc) {
      acc[0] = __builtin_amdgcn_mfma_f32_16x16x32_bf16(a[0][kc], b[kc], acc[0], 0, 0, 0);
      acc[1] = __builtin_amdgcn_mfma_f32_16x16x32_bf16(a[1][kc], b[kc], acc[1], 0, 0, 0);
    }
    const int tj0 = j0 + jt * 16;
    const int gj = tj0 + lr;
    const int lj = lab[gj];
    const bool overlap = (tj0 == i0) || (tj0 == i0 + 16);
#pragma unroll
    for (int rf = 0; rf < 2; ++rf)
#pragma unroll
      for (int r = 0; r < 4; ++r) {
        bool pos = (li[rf][r] == lj);
        if (overlap) pos = pos && (gibase[rf] + r != gj);
        if (__any(pos)) {
          float t = acc[rf][r] + l2i[rf][r];
          float x = __builtin_amdgcn_exp2f(t) + EPSV;
          float lf = __builtin_amdgcn_logf(x);
          lacc[rf][r] += pos ? lf : 0.0f;
        }
      }
  }
#pragma unroll
  for (int rf = 0; rf < 2; ++rf)
#pragma unroll
    for (int r = 0; r < 4; ++r) {
      float v = lacc[rf][r];
      v += __shfl_xor(v, 1); v += __shfl_xor(v, 2);
      v += __shfl_xor(v, 4); v += __shfl_xor(v, 8);
      if (lr == 0)
        ploss[(size_t)blockIdx.y * NROWS + gibase[rf] + r] = v;
    }
}

// ---------------- kernel 5: per-row finalize ----------------
__global__ __launch_bounds__(256) void row_finalize(
    const float* __restrict__ ploss, const int* __restrict__ lab,
    const int* __restrict__ cnt,
    float* __restrict__ rowloss, int* __restrict__ rowvalid) {
  int i = blockIdx.x * 256 + threadIdx.x;
  float l = 0.f;
#pragma unroll
  for (int k = 0; k < SPLIT; ++k) l += ploss[(size_t)k * NROWS + i];
  int np = cnt[lab[i]] - 1;
  rowvalid[i] = (np > 0) ? 1 : 0;
  rowloss[i] = (np > 0) ? (l * LN2F / (float)np) : 0.0f;
}

// ---------------- kernel 6: final scalar ----------------
__global__ __launch_bounds__(256) void final_reduce(
    const float* __restrict__ rowloss, const int* __restrict__ rowvalid,
    float* __restrict__ out) {
  __shared__ float sL[256];
  __shared__ int sV[256];
  int tid = threadIdx.x;
  float a = 0.f;
  int v = 0;
  for (int i = tid; i < NROWS; i += 256) {
    a += rowloss[i];
    v += rowvalid[i];
  }
  sL[tid] = a; sV[tid] = v;
  __syncthreads();
  for (int s = 128; s > 0; s >>= 1) {
    if (tid < s) { sL[tid] += sL[tid + s]; sV[tid] += sV[tid + s]; }
    __syncthreads();
  }
  if (tid == 0) {
    // N - nans + 1 == valid_count + 1
    out[0] = -sL[0] / (float)(sV[0] + 1);
  }
}

// ---------------- launch ----------------
extern "C" void kernel_launch(void* const* d_in, const int* in_sizes, int n_in,
                              void* d_out, int out_size, void* d_ws, size_t ws_size,
                              hipStream_t stream) {
  const float* feat = (const float*)d_in[0];
  const int* labels = (const int*)d_in[1];
  float* out = (float*)d_out;

  char* ws = (char*)d_ws;
  u16* g        = (u16*)(ws);                         // 2 MB
  float* pdenom = (float*)(ws + (2u << 20));          // 1 MB
  float* ploss  = (float*)(ws + (3u << 20));          // 1 MB
  float* li2    = (float*)(ws + (4u << 20));          // 32 KB
  int* cnt      = (int*)(ws + (4u << 20) + 32768);    // 512 B
  float* rowloss= (float*)(ws + (4u << 20) + 65536);  // 32 KB
  int* rowvalid = (int*)(ws + (4u << 20) + 98304);    // 32 KB

  norm_kernel<<<NROWS / 4, 256, 0, stream>>>(feat, g);
  hist_kernel<<<1, 256, 0, stream>>>(labels, cnt);
  denom_kernel<<<dim3(NROWS / 128, SPLIT), 256, 0, stream>>>(g, pdenom);
  denom_reduce<<<NROWS / 256, 256, 0, stream>>>(pdenom, li2);
  loss_kernel<<<dim3(NROWS / 128, SPLIT), 256, 0, stream>>>(g, labels, li2, ploss);
  row_finalize<<<NROWS / 256, 256, 0, stream>>>(ploss, labels, cnt, rowloss, rowvalid);
  final_reduce<<<1, 256, 0, stream>>>(rowloss, rowvalid, out);
}